// Round 1
// baseline (3866.944 us; speedup 1.0000x reference)
//
#include <hip/hip_runtime.h>
#include <hip/hip_bf16.h>

// Problem constants: B=64, T=2048, IN_F=128, H1=OUT_F=64, 4H=256
#define BB 64
#define TT 2048
#define INF 128
#define HH 64
#define GG 256  // 4*H

__device__ __forceinline__ float sigm(float x) { return 1.0f / (1.0f + __expf(-x)); }
__device__ __forceinline__ float tanh_f(float x) {
  float e = __expf(2.0f * x);
  return 1.0f - 2.0f / (e + 1.0f);
}
// Wave-uniform broadcast of lane l's value via v_readlane (SGPR path, no LDS).
__device__ __forceinline__ float bcast(float v, int l) {
  return __uint_as_float(__builtin_amdgcn_readlane(__float_as_uint(v), l));
}

// ---------------------------------------------------------------------------
// All hot loops are SOURCE-unrolled via macros: SROA runs before loop
// unrolling, so any variable array index sends the array to scratch (round
// 1-3: VGPR_Count 120/200/144 == spills). Literal indices -> constant GEPs
// -> arrays promoted to VGPRs.
// ---------------------------------------------------------------------------

// ---------------------------------------------------------------------------
// Kernel 1: xg1[m][n] = X[m,:].W_ih1[n,:] + b_ih1[n] + b_hh1[n]
// M=131072, N=256, K=128. Thread t owns W rows {t,128+t} in 256 VGPRs;
// x row lane-distributed (float2/lane), broadcast via readlane.
// 1024 blocks x 128 threads (128 rows/block -> 2 blocks/CU, 2 waves/SIMD
// so latency bubbles of one wave are filled by the other).
// ---------------------------------------------------------------------------
#define XWL1(I)                                                   \
  { float4 a = Wp[t * 32 + (I)];                                  \
    w0[4*(I)] = a.x; w0[4*(I)+1] = a.y; w0[4*(I)+2] = a.z; w0[4*(I)+3] = a.w; \
    float4 b = Wp[(128 + t) * 32 + (I)];                          \
    w1[4*(I)] = b.x; w1[4*(I)+1] = b.y; w1[4*(I)+2] = b.z; w1[4*(I)+3] = b.w; }
#define XWL4(I) XWL1(I) XWL1((I)+1) XWL1((I)+2) XWL1((I)+3)
#define XWLOAD XWL4(0) XWL4(4) XWL4(8) XWL4(12) XWL4(16) XWL4(20) XWL4(24) XWL4(28)

#define XD1(L)                                                    \
  { float xa = bcast(curx, (L)); float xb = bcast(cury, (L));     \
    a0e = fmaf(xa, w0[2*(L)],   a0e); a0o = fmaf(xb, w0[2*(L)+1], a0o); \
    a1e = fmaf(xa, w1[2*(L)],   a1e); a1o = fmaf(xb, w1[2*(L)+1], a1o); }
#define XD8(L) XD1(L) XD1((L)+1) XD1((L)+2) XD1((L)+3) XD1((L)+4) XD1((L)+5) XD1((L)+6) XD1((L)+7)
#define XDOT64 XD8(0) XD8(8) XD8(16) XD8(24) XD8(32) XD8(40) XD8(48) XD8(56)

__global__ __launch_bounds__(128, 1) void xgemm(const float* __restrict__ X,
                                                const float* __restrict__ W,
                                                const float* __restrict__ bi,
                                                const float* __restrict__ bh,
                                                float* __restrict__ XG) {
  const int t = threadIdx.x;            // 0..127
  const int lane = t & 63;
  const long m0 = (long)blockIdx.x * 128;

  float w0[INF], w1[INF];
  const float4* Wp = (const float4*)W;
  XWLOAD
  const float bias0 = bi[t] + bh[t];
  const float bias1 = bi[128 + t] + bh[128 + t];

  const float2* Xp = (const float2*)X;  // lane l holds k=2l,2l+1
  float2 cur = Xp[(size_t)m0 * 64 + lane];
  float2 nx1 = Xp[(size_t)(m0 + 1) * 64 + lane];

  for (int mi = 0; mi < 128; ++mi) {
    const long m = m0 + mi;
    float2 nx2 = make_float2(0.f, 0.f);
    if (mi + 2 < 128) nx2 = Xp[(size_t)(m + 2) * 64 + lane];

    const float curx = cur.x, cury = cur.y;
    float a0e = bias0, a0o = 0.f, a1e = bias1, a1o = 0.f;  // 4 indep chains
    XDOT64
    XG[(size_t)m * GG + t] = a0e + a0o;
    XG[(size_t)m * GG + 128 + t] = a1e + a1o;
    cur = nx1; nx1 = nx2;
  }
}

// ---------------------------------------------------------------------------
// Kernel 2: barrier-free wave-specialized LSTM pipeline.
//   W0: layer-1 recurrence -> x2 ring (flag batched every 2 steps).
//   W1+W3: layer-2 input dot, split by even/odd timestep (each wave gets
//          two step-times per dot -> off the bottleneck).
//   W2: Whh2.h2 (computed BEFORE the ring wait, with speculative a2x
//       prefetch when the cached flag already covers this step) + update.
// Sync: monotonic LDS counters with REGISTER CACHING (skip the volatile
// poll when the cached value already satisfies the target -> most steps do
// zero sync LDS reads), volatile spin otherwise, lgkmcnt(0) before publish.
// Ring depth 8 gives the slack that makes caching effective.
// ---------------------------------------------------------------------------
#define WL1(I)                                                                  \
  { float4 a = p[lane * 16 + (I)];                                              \
    wi[4*(I)] = a.x; wi[4*(I)+1] = a.y; wi[4*(I)+2] = a.z; wi[4*(I)+3] = a.w;   \
    float4 c = p[(64 + lane) * 16 + (I)];                                       \
    wf[4*(I)] = c.x; wf[4*(I)+1] = c.y; wf[4*(I)+2] = c.z; wf[4*(I)+3] = c.w;   \
    float4 d = p[(128 + lane) * 16 + (I)];                                      \
    wg[4*(I)] = d.x; wg[4*(I)+1] = d.y; wg[4*(I)+2] = d.z; wg[4*(I)+3] = d.w;   \
    float4 e = p[(192 + lane) * 16 + (I)];                                      \
    wo[4*(I)] = e.x; wo[4*(I)+1] = e.y; wo[4*(I)+2] = e.z; wo[4*(I)+3] = e.w; }
#define WL4(I) WL1(I) WL1((I)+1) WL1((I)+2) WL1((I)+3)
#define WLOAD WL4(0) WL4(4) WL4(8) WL4(12)

#define D1(K)                                              \
  { float hk = bcast(hv, (K));                             \
    ai = fmaf(hk, wi[(K)], ai); af = fmaf(hk, wf[(K)], af);\
    ag = fmaf(hk, wg[(K)], ag); ao = fmaf(hk, wo[(K)], ao); }
#define D8(K) D1(K) D1((K)+1) D1((K)+2) D1((K)+3) D1((K)+4) D1((K)+5) D1((K)+6) D1((K)+7)
#define DOT64 D8(0) D8(8) D8(16) D8(24) D8(32) D8(40) D8(48) D8(56)

__global__ __launch_bounds__(256, 1) void lstm2(const float* __restrict__ XG,
                                                const float* __restrict__ Whh1,
                                                const float* __restrict__ Wih2,
                                                const float* __restrict__ Whh2,
                                                const float* __restrict__ bi2,
                                                const float* __restrict__ bh2,
                                                const float* __restrict__ m1g,
                                                const float* __restrict__ m2g,
                                                float* __restrict__ out) {
  const int b = blockIdx.x;
  const int wid = threadIdx.x >> 6;
  const int lane = threadIdx.x & 63;

  __shared__ int f_w0, f_e, f_o, f_w2;              // monotonic step counters
  __shared__ __align__(16) float x2buf[8][HH];      // W0 -> W1/W3 ring
  __shared__ __align__(16) float a2xbuf[8][GG];     // W1/W3 -> W2 ring

  if (threadIdx.x == 0) { f_w0 = 0; f_e = 0; f_o = 0; f_w2 = 0; }
  __syncthreads();  // one-time

// Cached wait: only touch LDS when the cached value is insufficient.
// Always end with a compiler barrier so data reads can't be hoisted above
// the point where availability was established.
#define WAITC(seen, flag, tgt)                                  \
  do {                                                          \
    if ((seen) < (tgt)) {                                       \
      while (((seen) = *(volatile int*)&(flag)) < (tgt)) {}     \
    }                                                           \
    asm volatile("" ::: "memory");                              \
  } while (0)
#define PUBLISH(flag, val)                                      \
  do {                                                          \
    asm volatile("s_waitcnt lgkmcnt(0)" ::: "memory");          \
    if (lane == 0) *(volatile int*)&(flag) = (val);             \
  } while (0)
#define PUBLISHP(pflag, val)                                    \
  do {                                                          \
    asm volatile("s_waitcnt lgkmcnt(0)" ::: "memory");          \
    if (lane == 0) *(pflag) = (val);                            \
  } while (0)

  if (wid == 0) {
    // ---- stage 0: layer-1 recurrence (2 steps per iteration) ----
    float wi[HH], wf[HH], wg[HH], wo[HH];
    const float4* p = (const float4*)Whh1;
    WLOAD
    const float m1 = m1g[b * HH + lane];
    const float* xgp = XG + (size_t)b * TT * GG;

    float a0 = xgp[lane], a1 = xgp[64 + lane], a2 = xgp[128 + lane], a3 = xgp[192 + lane];
    float b0 = xgp[GG + lane], b1 = xgp[GG + 64 + lane], b2 = xgp[GG + 128 + lane], b3 = xgp[GG + 192 + lane];

    float h1 = 0.f, c1 = 0.f;
    int seen_e = 0, seen_o = 0;
    for (int s = 0; s < TT; s += 2) {
      // prefetch steps s+2, s+3 (consumed next iteration; ~1 pair-time > HBM lat)
      float p0 = 0.f, p1 = 0.f, p2 = 0.f, p3 = 0.f;
      float q0 = 0.f, q1 = 0.f, q2 = 0.f, q3 = 0.f;
      if (s + 2 < TT) {
        const float* q = xgp + (size_t)(s + 2) * GG;
        p0 = q[lane]; p1 = q[64 + lane]; p2 = q[128 + lane]; p3 = q[192 + lane];
        const float* r = q + GG;
        q0 = r[lane]; q1 = r[64 + lane]; q2 = r[128 + lane]; q3 = r[192 + lane];
      }

      // ring slots (s&7) even / ((s+1)&7) odd free? (prev occupant = s-8 / s-7)
      WAITC(seen_e, f_e, s - 7);
      WAITC(seen_o, f_o, s - 6);

      {  // step s
        const float hv = h1;
        float ai = a0, af = a1, ag = a2, ao = a3;
        DOT64
        c1 = sigm(af) * c1 + sigm(ai) * tanh_f(ag);
        h1 = sigm(ao) * tanh_f(c1);
        x2buf[s & 7][lane] = h1 * m1;
      }
      {  // step s+1
        const float hv = h1;
        float ai = b0, af = b1, ag = b2, ao = b3;
        DOT64
        c1 = sigm(af) * c1 + sigm(ai) * tanh_f(ag);
        h1 = sigm(ao) * tanh_f(c1);
        x2buf[(s + 1) & 7][lane] = h1 * m1;
      }
      PUBLISH(f_w0, s + 2);  // one flag write per pair

      a0 = p0; a1 = p1; a2 = p2; a3 = p3;
      b0 = q0; b1 = q1; b2 = q2; b3 = q3;
    }
  } else if (wid == 2) {
    // ---- stage 2: layer-2 recurrent dot + update + store ----
    float wi[HH], wf[HH], wg[HH], wo[HH];
    const float4* p = (const float4*)Whh2;
    WLOAD
    const float m2 = m2g[b * HH + lane];
    float* ob = out + (size_t)b * TT * HH;

    float h2 = 0.f, c2 = 0.f;
    int seen_e = 0, seen_o = 0;
    for (int s = 0; s < TT; ++s) {
      const int odd = s & 1;
      // speculative prefetch of a2x when the cached flag already covers s
      const bool pre = odd ? (seen_o >= s + 1) : (seen_e >= s + 1);
      float xi, xf, xg, xo;
      if (pre) {
        asm volatile("" ::: "memory");
        xi = a2xbuf[s & 7][lane];
        xf = a2xbuf[s & 7][64 + lane];
        xg = a2xbuf[s & 7][128 + lane];
        xo = a2xbuf[s & 7][192 + lane];
      }

      // Whh2 . h2(s-1): no dependence on W1/W3 -> compute BEFORE the wait.
      const float hv = h2;
      float ai = 0.f, af = 0.f, ag = 0.f, ao = 0.f;
      DOT64

      if (!pre) {
        if (odd) { WAITC(seen_o, f_o, s + 1); }
        else     { WAITC(seen_e, f_e, s + 1); }
        xi = a2xbuf[s & 7][lane];
        xf = a2xbuf[s & 7][64 + lane];
        xg = a2xbuf[s & 7][128 + lane];
        xo = a2xbuf[s & 7][192 + lane];
      }
      ai += xi; af += xf; ag += xg; ao += xo;

      // slot consumed (lgkmcnt(0) inside PUBLISH drains the reads) -> free it
      // before the activation/store tail.
      PUBLISH(f_w2, s + 1);

      c2 = sigm(af) * c2 + sigm(ai) * tanh_f(ag);
      h2 = sigm(ao) * tanh_f(c2);
      ob[(size_t)s * HH + lane] = fmaxf(h2 * m2, 0.f);
    }
  } else {
    // ---- stage 1: layer-2 input dot, split by timestep parity ----
    // wid==1 -> even steps, wid==3 -> odd steps. Each wave has two
    // step-times per 640-cycle dot -> no longer the pipeline bottleneck.
    float wi[HH], wf[HH], wg[HH], wo[HH];
    const float4* p = (const float4*)Wih2;
    WLOAD
    const float bi_i = bi2[lane] + bh2[lane];
    const float bi_f = bi2[64 + lane] + bh2[64 + lane];
    const float bi_g = bi2[128 + lane] + bh2[128 + lane];
    const float bi_o = bi2[192 + lane] + bh2[192 + lane];

    const int par = (wid == 3);
    volatile int* const myflag = par ? &f_o : &f_e;
    int seen0 = 0, seen2 = 0;
    for (int s = par; s < TT; s += 2) {
      WAITC(seen0, f_w0, s + 1);
      const float hv = x2buf[s & 7][lane];

      float ai = bi_i, af = bi_f, ag = bi_g, ao = bi_o;
      DOT64

      WAITC(seen2, f_w2, s - 7);  // a2x slot (s&7) free? (prev occupant s-8)
      a2xbuf[s & 7][lane] = ai;
      a2xbuf[s & 7][64 + lane] = af;
      a2xbuf[s & 7][128 + lane] = ag;
      a2xbuf[s & 7][192 + lane] = ao;
      PUBLISHP(myflag, s + 1);
    }
  }
#undef WAITC
#undef PUBLISH
#undef PUBLISHP
}

extern "C" void kernel_launch(void* const* d_in, const int* in_sizes, int n_in,
                              void* d_out, int out_size, void* d_ws, size_t ws_size,
                              hipStream_t stream) {
  (void)in_sizes; (void)n_in; (void)out_size; (void)ws_size;
  const float* x     = (const float*)d_in[0];
  const float* W_ih1 = (const float*)d_in[1];
  const float* W_hh1 = (const float*)d_in[2];
  const float* b_ih1 = (const float*)d_in[3];
  const float* b_hh1 = (const float*)d_in[4];
  const float* W_ih2 = (const float*)d_in[5];
  const float* W_hh2 = (const float*)d_in[6];
  const float* b_ih2 = (const float*)d_in[7];
  const float* b_hh2 = (const float*)d_in[8];
  const float* mask1 = (const float*)d_in[9];
  const float* mask2 = (const float*)d_in[10];
  float* out = (float*)d_out;

  float* xg1 = (float*)d_ws;  // B*T*4H fp32 = 134,217,728 bytes

  xgemm<<<dim3(BB * TT / 128), dim3(128), 0, stream>>>(x, W_ih1, b_ih1, b_hh1, xg1);
  lstm2<<<dim3(BB), dim3(256), 0, stream>>>(xg1, W_hh1, W_ih2, W_hh2, b_ih2, b_hh2,
                                            mask1, mask2, out);
}

// Round 2
// 2729.085 us; speedup vs baseline: 1.4169x; 1.4169x over previous
//
#include <hip/hip_runtime.h>
#include <hip/hip_bf16.h>

// Problem constants: B=64, T=2048, IN_F=128, H1=OUT_F=64, 4H=256
#define BB 64
#define TT 2048
#define INF 128
#define HH 64
#define GG 256  // 4*H

__device__ __forceinline__ float sigm(float x) { return 1.0f / (1.0f + __expf(-x)); }
__device__ __forceinline__ float tanh_f(float x) {
  float e = __expf(2.0f * x);
  return 1.0f - 2.0f / (e + 1.0f);
}
// Wave-uniform broadcast of lane l's value via v_readlane (SGPR path, no LDS).
__device__ __forceinline__ float bcast(float v, int l) {
  return __uint_as_float(__builtin_amdgcn_readlane(__float_as_uint(v), l));
}
// Cell update shared by BOTH waves of a team: explicit op DAG so the two
// redundant (h,c) copies stay bit-identical (inputs are the same published
// fp32 bits; same inline function -> same instruction DAG in both branches).
__device__ __forceinline__ void lstm_upd(float Si, float Sf, float Tg, float So,
                                         float& c, float& h) {
  c = fmaf(Sf, c, Si * Tg);
  h = So * tanh_f(c);
}

// ---------------------------------------------------------------------------
// KEY CONSTRAINT (round-1 post-mortem): a wave may own at most 128 weight
// floats. 256-float arrays spill to AGPRs (VGPR_Count 144 < 256 floats in
// round 0 proves it) and every fma then pays a v_accvgpr_read: DOT64 becomes
// ~1150cy instead of 640. All dots below are 2-gate (128 regs, 384cy).
// Source-unrolled via macros: literal indices -> SROA -> registers.
// ---------------------------------------------------------------------------

// 2-gate weight load: lane owns row (base+lane) -> wA, row (base+64+lane) -> wB.
// p = (const float4*)(W + base*HH); row = 16 float4.
#define WL2(I)                                                                   \
  { float4 a_ = p[lane * 16 + (I)];                                              \
    wA[4*(I)] = a_.x; wA[4*(I)+1] = a_.y; wA[4*(I)+2] = a_.z; wA[4*(I)+3] = a_.w;\
    float4 b_ = p[(64 + lane) * 16 + (I)];                                       \
    wB[4*(I)] = b_.x; wB[4*(I)+1] = b_.y; wB[4*(I)+2] = b_.z; wB[4*(I)+3] = b_.w; }
#define WL2x4(I) WL2(I) WL2((I)+1) WL2((I)+2) WL2((I)+3)
#define WLOAD2 WL2x4(0) WL2x4(4) WL2x4(8) WL2x4(12)

#define G1(K)                                                    \
  { float hk = bcast(hv, (K));                                   \
    aA = fmaf(hk, wA[(K)], aA); aB = fmaf(hk, wB[(K)], aB); }
#define G8(K) G1(K) G1((K)+1) G1((K)+2) G1((K)+3) G1((K)+4) G1((K)+5) G1((K)+6) G1((K)+7)
#define DOT2G G8(0) G8(8) G8(16) G8(24) G8(32) G8(40) G8(48) G8(56)

// ---------------------------------------------------------------------------
// Kernel 1: xg1[m][n] = X[m,:].W_ih1[n,:] + b_ih1[n] + b_hh1[n]
// One W row per thread (128 VGPRs - no AGPR spill). 256 threads = all 256
// outputs; 512 blocks x 256 rows of m; 2 blocks/CU -> 2 waves/SIMD.
// ---------------------------------------------------------------------------
#define YW1(I) { float4 a_ = Wp[t * 32 + (I)];                                   \
    wr[4*(I)] = a_.x; wr[4*(I)+1] = a_.y; wr[4*(I)+2] = a_.z; wr[4*(I)+3] = a_.w; }
#define YW4(I) YW1(I) YW1((I)+1) YW1((I)+2) YW1((I)+3)
#define YWLOAD YW4(0) YW4(4) YW4(8) YW4(12) YW4(16) YW4(20) YW4(24) YW4(28)

#define YD1(L)                                                   \
  { float xa = bcast(curx, (L)); float xb = bcast(cury, (L));    \
    ae = fmaf(xa, wr[2*(L)], ae); ao = fmaf(xb, wr[2*(L)+1], ao); }
#define YD8(L) YD1(L) YD1((L)+1) YD1((L)+2) YD1((L)+3) YD1((L)+4) YD1((L)+5) YD1((L)+6) YD1((L)+7)
#define YDOT64 YD8(0) YD8(8) YD8(16) YD8(24) YD8(32) YD8(40) YD8(48) YD8(56)

__global__ __launch_bounds__(256, 1) void xgemm(const float* __restrict__ X,
                                                const float* __restrict__ W,
                                                const float* __restrict__ bi,
                                                const float* __restrict__ bh,
                                                float* __restrict__ XG) {
  const int t = threadIdx.x;            // 0..255 = owned W row
  const int lane = t & 63;
  const long m0 = (long)blockIdx.x * 256;

  float wr[INF];
  const float4* Wp = (const float4*)W;
  YWLOAD
  const float bias = bi[t] + bh[t];

  const float2* Xp = (const float2*)X;  // lane l holds k=2l,2l+1
  float2 cur = Xp[(size_t)m0 * 64 + lane];
  float2 nx1 = Xp[(size_t)(m0 + 1) * 64 + lane];

  for (int mi = 0; mi < 256; ++mi) {
    const long m = m0 + mi;
    float2 nx2 = make_float2(0.f, 0.f);
    if (mi + 2 < 256) nx2 = Xp[(size_t)(m + 2) * 64 + lane];

    const float curx = cur.x, cury = cur.y;
    float ae = bias, ao = 0.f;
    YDOT64
    XG[(size_t)m * GG + t] = ae + ao;
    cur = nx1; nx1 = nx2;
  }
}

// ---------------------------------------------------------------------------
// Kernel 2: 6-wave pipeline, all dots 2-gate (128 weight VGPRs/wave).
//  wid 2: A0  L1 gates i,f + redundant (h1,c1) + x2 publish      (SIMD2 alone)
//  wid 0: B0  L1 gates g,o + redundant (h1,c1)                   (SIMD0)
//  wid 4: X1  L2 input dot gates i,f -> a2xA ring                (SIMD0)
//  wid 5: X2  L2 input dot gates g,o -> a2xB ring                (SIMD1)
//  wid 1: B2  L2 gates g,o + redundant (h2,c2)                   (SIMD1)
//  wid 3: A2  L2 gates i,f + redundant (h2,c2) + out store       (SIMD3 alone)
// Teams exchange ACTIVATED gate pairs symmetrically (publish own -> read
// partner's): ONE parallel LDS hop per step instead of two serial ones.
// Sync: monotonic LDS counters + register caching; lgkmcnt(0) before publish.
// ---------------------------------------------------------------------------
__global__ __launch_bounds__(384, 1) void lstm2(const float* __restrict__ XG,
                                                const float* __restrict__ Whh1,
                                                const float* __restrict__ Wih2,
                                                const float* __restrict__ Whh2,
                                                const float* __restrict__ bi2,
                                                const float* __restrict__ bh2,
                                                const float* __restrict__ m1g,
                                                const float* __restrict__ m2g,
                                                float* __restrict__ out) {
  const int b = blockIdx.x;
  const int wid = threadIdx.x >> 6;
  const int lane = threadIdx.x & 63;

  __shared__ int f_0A, f_0B, f_h1, f_xA, f_xB, f_2A, f_2B;
  __shared__ __align__(16) float ex0A[2][2 * HH];  // A0 -> B0 : S_i, S_f
  __shared__ __align__(16) float ex0B[2][2 * HH];  // B0 -> A0 : T_g, S_o
  __shared__ __align__(16) float ex2A[2][2 * HH];  // A2 -> B2 : S_i, S_f
  __shared__ __align__(16) float ex2B[2][2 * HH];  // B2 -> A2 : T_g, S_o
  __shared__ __align__(16) float x2buf[8][HH];     // A0 -> X1,X2
  __shared__ __align__(16) float a2xA[8][2 * HH];  // X1 -> A2 : ai, af
  __shared__ __align__(16) float a2xB[8][2 * HH];  // X2 -> B2 : ag, ao

  if (threadIdx.x == 0) { f_0A = 0; f_0B = 0; f_h1 = 0; f_xA = 0; f_xB = 0; f_2A = 0; f_2B = 0; }
  __syncthreads();  // one-time

// Cached wait: touch LDS only when cached value insufficient (flags monotonic).
#define WAITC(seen, flag, tgt)                                  \
  do {                                                          \
    if ((seen) < (tgt)) {                                       \
      while (((seen) = *(volatile int*)&(flag)) < (tgt)) {}     \
    }                                                           \
    asm volatile("" ::: "memory");                              \
  } while (0)
#define PUBLISH(flag, val)                                      \
  do {                                                          \
    asm volatile("s_waitcnt lgkmcnt(0)" ::: "memory");          \
    if (lane == 0) *(volatile int*)&(flag) = (val);             \
  } while (0)

  if (wid == 2) {
    // ---- A0: L1 gates i,f; owns x2 publish ----
    float wA[HH], wB[HH];
    const float4* p = (const float4*)Whh1;            // rows 0..127
    WLOAD2
    const float m1 = m1g[b * HH + lane];
    const float* xgp = XG + (size_t)b * TT * GG;

    float xi0 = xgp[lane],      xf0 = xgp[64 + lane];
    float xi1 = xgp[GG + lane], xf1 = xgp[GG + 64 + lane];

    float h1 = 0.f, c1 = 0.f;
    int s0B = 0, sxa = 0, sxb = 0;
    for (int s = 0; s < TT; ++s) {
      float xi2 = 0.f, xf2 = 0.f;
      if (s + 2 < TT) {
        const float* q = xgp + (size_t)(s + 2) * GG;
        xi2 = q[lane]; xf2 = q[64 + lane];
      }
      const float hv = h1;
      float aA = xi0, aB = xf0;
      DOT2G
      const float Si = sigm(aA), Sf = sigm(aB);
      ex0A[s & 1][lane] = Si; ex0A[s & 1][64 + lane] = Sf;
      PUBLISH(f_0A, s + 1);                  // publish BEFORE waiting (no deadlock)
      WAITC(s0B, f_0B, s + 1);
      const float Tg = ex0B[s & 1][lane], So = ex0B[s & 1][64 + lane];
      lstm_upd(Si, Sf, Tg, So, c1, h1);
      // x2 ring slot (s&7) free? occupant s-8 consumed by both X waves.
      WAITC(sxa, f_xA, s - 7);
      WAITC(sxb, f_xB, s - 7);
      x2buf[s & 7][lane] = h1 * m1;
      PUBLISH(f_h1, s + 1);
      xi0 = xi1; xf0 = xf1; xi1 = xi2; xf1 = xf2;
    }
  } else if (wid == 0) {
    // ---- B0: L1 gates g,o ----
    float wA[HH], wB[HH];
    const float4* p = (const float4*)(Whh1 + 128 * HH);  // rows 128..255
    WLOAD2
    const float* xgp = XG + (size_t)b * TT * GG;

    float xg0 = xgp[128 + lane],      xo0 = xgp[192 + lane];
    float xg1 = xgp[GG + 128 + lane], xo1 = xgp[GG + 192 + lane];

    float h1 = 0.f, c1 = 0.f;
    int s0A = 0;
    for (int s = 0; s < TT; ++s) {
      float xg2 = 0.f, xo2 = 0.f;
      if (s + 2 < TT) {
        const float* q = xgp + (size_t)(s + 2) * GG;
        xg2 = q[128 + lane]; xo2 = q[192 + lane];
      }
      const float hv = h1;
      float aA = xg0, aB = xo0;
      DOT2G
      const float Tg = tanh_f(aA), So = sigm(aB);
      ex0B[s & 1][lane] = Tg; ex0B[s & 1][64 + lane] = So;
      PUBLISH(f_0B, s + 1);
      WAITC(s0A, f_0A, s + 1);
      const float Si = ex0A[s & 1][lane], Sf = ex0A[s & 1][64 + lane];
      lstm_upd(Si, Sf, Tg, So, c1, h1);
      xg0 = xg1; xo0 = xo1; xg1 = xg2; xo1 = xo2;
    }
  } else if (wid == 4) {
    // ---- X1: Wih2 gates i,f over x2 ----
    float wA[HH], wB[HH];
    const float4* p = (const float4*)Wih2;               // rows 0..127
    WLOAD2
    const float biA = bi2[lane] + bh2[lane];
    const float biB = bi2[64 + lane] + bh2[64 + lane];

    int sh = 0, sc = 0;
    for (int s = 0; s < TT; ++s) {
      WAITC(sh, f_h1, s + 1);
      const float hv = x2buf[s & 7][lane];
      float aA = biA, aB = biB;
      DOT2G
      WAITC(sc, f_2A, s - 7);   // A2 consumed a2xA slot s-8 before f_2A = s-7
      a2xA[s & 7][lane] = aA; a2xA[s & 7][64 + lane] = aB;
      PUBLISH(f_xA, s + 1);
    }
  } else if (wid == 5) {
    // ---- X2: Wih2 gates g,o over x2 ----
    float wA[HH], wB[HH];
    const float4* p = (const float4*)(Wih2 + 128 * HH);  // rows 128..255
    WLOAD2
    const float biA = bi2[128 + lane] + bh2[128 + lane];
    const float biB = bi2[192 + lane] + bh2[192 + lane];

    int sh = 0, sc = 0;
    for (int s = 0; s < TT; ++s) {
      WAITC(sh, f_h1, s + 1);
      const float hv = x2buf[s & 7][lane];
      float aA = biA, aB = biB;
      DOT2G
      WAITC(sc, f_2B, s - 7);   // B2 consumed a2xB slot s-8 before f_2B = s-7
      a2xB[s & 7][lane] = aA; a2xB[s & 7][64 + lane] = aB;
      PUBLISH(f_xB, s + 1);
    }
  } else if (wid == 3) {
    // ---- A2: L2 gates i,f; owns out store ----
    float wA[HH], wB[HH];
    const float4* p = (const float4*)Whh2;               // rows 0..127
    WLOAD2
    const float m2v = m2g[b * HH + lane];
    float* ob = out + (size_t)b * TT * HH;

    float h2 = 0.f, c2 = 0.f;
    int sx = 0, s2B = 0;
    for (int s = 0; s < TT; ++s) {
      WAITC(sx, f_xA, s + 1);
      const float pi = a2xA[s & 7][lane], pf = a2xA[s & 7][64 + lane];  // issue early
      const float hv = h2;
      float aA = 0.f, aB = 0.f;
      DOT2G                    // read latency of pi/pf hides under the dot
      aA += pi; aB += pf;
      const float Si = sigm(aA), Sf = sigm(aB);
      ex2A[s & 1][lane] = Si; ex2A[s & 1][64 + lane] = Sf;
      PUBLISH(f_2A, s + 1);    // also signals a2xA slot s consumed
      WAITC(s2B, f_2B, s + 1);
      const float Tg = ex2B[s & 1][lane], So = ex2B[s & 1][64 + lane];
      lstm_upd(Si, Sf, Tg, So, c2, h2);
      ob[(size_t)s * HH + lane] = fmaxf(h2 * m2v, 0.f);
    }
  } else {
    // ---- B2 (wid==1): L2 gates g,o ----
    float wA[HH], wB[HH];
    const float4* p = (const float4*)(Whh2 + 128 * HH);  // rows 128..255
    WLOAD2

    float h2 = 0.f, c2 = 0.f;
    int sx = 0, s2A = 0;
    for (int s = 0; s < TT; ++s) {
      WAITC(sx, f_xB, s + 1);
      const float pg = a2xB[s & 7][lane], po = a2xB[s & 7][64 + lane];
      const float hv = h2;
      float aA = 0.f, aB = 0.f;
      DOT2G
      aA += pg; aB += po;
      const float Tg = tanh_f(aA), So = sigm(aB);
      ex2B[s & 1][lane] = Tg; ex2B[s & 1][64 + lane] = So;
      PUBLISH(f_2B, s + 1);    // also signals a2xB slot s consumed
      WAITC(s2A, f_2A, s + 1);
      const float Si = ex2A[s & 1][lane], Sf = ex2A[s & 1][64 + lane];
      lstm_upd(Si, Sf, Tg, So, c2, h2);
    }
  }
#undef WAITC
#undef PUBLISH
}

extern "C" void kernel_launch(void* const* d_in, const int* in_sizes, int n_in,
                              void* d_out, int out_size, void* d_ws, size_t ws_size,
                              hipStream_t stream) {
  (void)in_sizes; (void)n_in; (void)out_size; (void)ws_size;
  const float* x     = (const float*)d_in[0];
  const float* W_ih1 = (const float*)d_in[1];
  const float* W_hh1 = (const float*)d_in[2];
  const float* b_ih1 = (const float*)d_in[3];
  const float* b_hh1 = (const float*)d_in[4];
  const float* W_ih2 = (const float*)d_in[5];
  const float* W_hh2 = (const float*)d_in[6];
  const float* b_ih2 = (const float*)d_in[7];
  const float* b_hh2 = (const float*)d_in[8];
  const float* mask1 = (const float*)d_in[9];
  const float* mask2 = (const float*)d_in[10];
  float* out = (float*)d_out;

  float* xg1 = (float*)d_ws;  // B*T*4H fp32 = 134,217,728 bytes

  xgemm<<<dim3(BB * TT / 256), dim3(256), 0, stream>>>(x, W_ih1, b_ih1, b_hh1, xg1);
  lstm2<<<dim3(BB), dim3(384), 0, stream>>>(xg1, W_hh1, W_ih2, W_hh2, b_ih2, b_hh2,
                                            mask1, mask2, out);
}

// Round 3
// 2442.462 us; speedup vs baseline: 1.5832x; 1.1173x over previous
//
#include <hip/hip_runtime.h>
#include <hip/hip_bf16.h>

// Problem constants: B=64, T=2048, IN_F=128, H1=OUT_F=64, 4H=256
#define BB 64
#define TT 2048
#define INF 128
#define HH 64
#define GG 256  // 4*H

__device__ __forceinline__ float sigm(float x) { return 1.0f / (1.0f + __expf(-x)); }
__device__ __forceinline__ float tanh_f(float x) {
  float e = __expf(2.0f * x);
  return 1.0f - 2.0f / (e + 1.0f);
}
// Wave-uniform broadcast of lane l's value via v_readlane (SGPR path, no LDS).
__device__ __forceinline__ float bcast(float v, int l) {
  return __uint_as_float(__builtin_amdgcn_readlane(__float_as_uint(v), l));
}

// ---------------------------------------------------------------------------
// Measured constants driving this design (r0/r1/r2 post-mortems):
//  - non-cached LDS flag poll ~400-600cy; data read ~120cy; publish ~100-150cy
//    -> a per-step cross-wave exchange costs MORE than the dot-time it saves.
//  - weights beyond the arch-VGPR window go to AGPRs; each use pays a
//    v_accvgpr_read -> 256-float DOT64 ~1150cy issue.
//  - two dot-waves on one SIMD double each other's wall time.
// Therefore: monolithic recurrence waves (zero polls on their own critical
// path), parity-split feed-forward waves (2x budget -> polls cached),
// one wave per SIMD, flag caching everywhere, depth-8 rings.
// ---------------------------------------------------------------------------

// Full 4-gate weight load: lane owns rows lane / 64+lane / 128+lane / 192+lane.
#define WL1(I)                                                                  \
  { float4 a = p[lane * 16 + (I)];                                              \
    wi[4*(I)] = a.x; wi[4*(I)+1] = a.y; wi[4*(I)+2] = a.z; wi[4*(I)+3] = a.w;   \
    float4 c = p[(64 + lane) * 16 + (I)];                                       \
    wf[4*(I)] = c.x; wf[4*(I)+1] = c.y; wf[4*(I)+2] = c.z; wf[4*(I)+3] = c.w;   \
    float4 d = p[(128 + lane) * 16 + (I)];                                      \
    wg[4*(I)] = d.x; wg[4*(I)+1] = d.y; wg[4*(I)+2] = d.z; wg[4*(I)+3] = d.w;   \
    float4 e = p[(192 + lane) * 16 + (I)];                                      \
    wo[4*(I)] = e.x; wo[4*(I)+1] = e.y; wo[4*(I)+2] = e.z; wo[4*(I)+3] = e.w; }
#define WL4(I) WL1(I) WL1((I)+1) WL1((I)+2) WL1((I)+3)
#define WLOAD WL4(0) WL4(4) WL4(8) WL4(12)

#define D1(K)                                              \
  { float hk = bcast(hv, (K));                             \
    ai = fmaf(hk, wi[(K)], ai); af = fmaf(hk, wf[(K)], af);\
    ag = fmaf(hk, wg[(K)], ag); ao = fmaf(hk, wo[(K)], ao); }
#define D8(K) D1(K) D1((K)+1) D1((K)+2) D1((K)+3) D1((K)+4) D1((K)+5) D1((K)+6) D1((K)+7)
#define DOT64 D8(0) D8(8) D8(16) D8(24) D8(32) D8(40) D8(48) D8(56)

// ---------------------------------------------------------------------------
// Kernel 1: xg1[m][n] = X[m,:].W_ih1[n,:] + b_ih1[n] + b_hh1[n]
// One W row per thread (128 floats). 256 threads = all 256 outputs;
// 512 blocks x 256 rows; 2 blocks/CU.  (unchanged from round 2: ~320us)
// ---------------------------------------------------------------------------
#define YW1(I) { float4 a_ = Wp[t * 32 + (I)];                                   \
    wr[4*(I)] = a_.x; wr[4*(I)+1] = a_.y; wr[4*(I)+2] = a_.z; wr[4*(I)+3] = a_.w; }
#define YW4(I) YW1(I) YW1((I)+1) YW1((I)+2) YW1((I)+3)
#define YWLOAD YW4(0) YW4(4) YW4(8) YW4(12) YW4(16) YW4(20) YW4(24) YW4(28)

#define YD1(L)                                                   \
  { float xa = bcast(curx, (L)); float xb = bcast(cury, (L));    \
    ae = fmaf(xa, wr[2*(L)], ae); ao = fmaf(xb, wr[2*(L)+1], ao); }
#define YD8(L) YD1(L) YD1((L)+1) YD1((L)+2) YD1((L)+3) YD1((L)+4) YD1((L)+5) YD1((L)+6) YD1((L)+7)
#define YDOT64 YD8(0) YD8(8) YD8(16) YD8(24) YD8(32) YD8(40) YD8(48) YD8(56)

__global__ __launch_bounds__(256, 1) void xgemm(const float* __restrict__ X,
                                                const float* __restrict__ W,
                                                const float* __restrict__ bi,
                                                const float* __restrict__ bh,
                                                float* __restrict__ XG) {
  const int t = threadIdx.x;            // 0..255 = owned W row
  const int lane = t & 63;
  const long m0 = (long)blockIdx.x * 256;

  float wr[INF];
  const float4* Wp = (const float4*)W;
  YWLOAD
  const float bias = bi[t] + bh[t];

  const float2* Xp = (const float2*)X;  // lane l holds k=2l,2l+1
  float2 cur = Xp[(size_t)m0 * 64 + lane];
  float2 nx1 = Xp[(size_t)(m0 + 1) * 64 + lane];

  for (int mi = 0; mi < 256; ++mi) {
    const long m = m0 + mi;
    float2 nx2 = make_float2(0.f, 0.f);
    if (mi + 2 < 256) nx2 = Xp[(size_t)(m + 2) * 64 + lane];

    const float curx = cur.x, cury = cur.y;
    float ae = bias, ao = 0.f;
    YDOT64
    XG[(size_t)m * GG + t] = ae + ao;
    cur = nx1; nx1 = nx2;
  }
}

// ---------------------------------------------------------------------------
// Kernel 2: 4-wave pipeline, one wave per SIMD.
//  wid 0: W0  L1 recurrence, full DOT64, -> x2 ring          (SIMD0)
//  wid 1: Xe  Wih2 dot, even steps       -> a2x ring         (SIMD1)
//  wid 2: Xo  Wih2 dot, odd  steps       -> a2x ring         (SIMD2)
//  wid 3: W2  L2 recurrence, full DOT64, a2x read BEFORE dot (SIMD3)
// Recurrence waves have ZERO cross-wave polls on their critical path in
// steady state (ring-slot checks are cached); X waves have 2 step-times
// per dot so their polls/writes are absorbed.
// ---------------------------------------------------------------------------
__global__ __attribute__((amdgpu_flat_work_group_size(256, 256),
                          amdgpu_waves_per_eu(1, 1)))
void lstm2(const float* __restrict__ XG,
           const float* __restrict__ Whh1,
           const float* __restrict__ Wih2,
           const float* __restrict__ Whh2,
           const float* __restrict__ bi2,
           const float* __restrict__ bh2,
           const float* __restrict__ m1g,
           const float* __restrict__ m2g,
           float* __restrict__ out) {
  const int b = blockIdx.x;
  const int wid = threadIdx.x >> 6;
  const int lane = threadIdx.x & 63;

  __shared__ int f_h1, f_xe, f_xo, f_2;             // monotonic step counters
  __shared__ __align__(16) float x2buf[8][HH];      // W0 -> Xe/Xo ring
  __shared__ __align__(16) float a2xbuf[8][GG];     // Xe/Xo -> W2 ring

  if (threadIdx.x == 0) { f_h1 = 0; f_xe = 0; f_xo = 0; f_2 = 0; }
  __syncthreads();  // one-time

// Cached wait: touch LDS only when cached value insufficient (flags monotonic).
#define WAITC(seen, flag, tgt)                                  \
  do {                                                          \
    if ((seen) < (tgt)) {                                       \
      while (((seen) = *(volatile int*)&(flag)) < (tgt)) {}     \
    }                                                           \
    asm volatile("" ::: "memory");                              \
  } while (0)
#define PUBLISH(flag, val)                                      \
  do {                                                          \
    asm volatile("s_waitcnt lgkmcnt(0)" ::: "memory");          \
    if (lane == 0) *(volatile int*)&(flag) = (val);             \
  } while (0)

  if (wid == 0) {
    // ---- W0: layer-1 recurrence (monolithic) ----
    float wi[HH], wf[HH], wg[HH], wo[HH];
    const float4* p = (const float4*)Whh1;
    WLOAD
    const float m1 = m1g[b * HH + lane];
    const float* xgp = XG + (size_t)b * TT * GG;

    float cur0 = xgp[lane], cur1 = xgp[64 + lane], cur2 = xgp[128 + lane], cur3 = xgp[192 + lane];
    float n10 = xgp[GG + lane], n11 = xgp[GG + 64 + lane], n12 = xgp[GG + 128 + lane], n13 = xgp[GG + 192 + lane];

    float h1 = 0.f, c1 = 0.f;
    int sxe = 0, sxo = 0;
    for (int s = 0; s < TT; ++s) {
      float n20 = 0.f, n21 = 0.f, n22 = 0.f, n23 = 0.f;
      if (s + 2 < TT) {
        const float* q = xgp + (size_t)(s + 2) * GG;
        n20 = q[lane]; n21 = q[64 + lane]; n22 = q[128 + lane]; n23 = q[192 + lane];
      }

      const float hv = h1;
      float ai = cur0, af = cur1, ag = cur2, ao = cur3;
      DOT64
      c1 = sigm(af) * c1 + sigm(ai) * tanh_f(ag);
      h1 = sigm(ao) * tanh_f(c1);

      // x2 ring slot (s&7) free? prev occupant s-8 (same parity) consumed
      // when its X wave published s-7. Cached in steady state.
      if (s & 1) { WAITC(sxo, f_xo, s - 7); }
      else       { WAITC(sxe, f_xe, s - 7); }
      x2buf[s & 7][lane] = h1 * m1;
      PUBLISH(f_h1, s + 1);

      cur0 = n10; cur1 = n11; cur2 = n12; cur3 = n13;
      n10 = n20; n11 = n21; n12 = n22; n13 = n23;
    }
  } else if (wid == 3) {
    // ---- W2: layer-2 recurrence (monolithic) + store ----
    float wi[HH], wf[HH], wg[HH], wo[HH];
    const float4* p = (const float4*)Whh2;
    WLOAD
    const float m2v = m2g[b * HH + lane];
    float* ob = out + (size_t)b * TT * HH;

    float h2 = 0.f, c2 = 0.f;
    int sxe = 0, sxo = 0;
    for (int s = 0; s < TT; ++s) {
      // a2x for step s ready? X waves run ~1 step ahead -> cached mostly.
      if (s & 1) { WAITC(sxo, f_xo, s + 1); }
      else       { WAITC(sxe, f_xe, s + 1); }
      // issue the 4 reads NOW; 120cy latency hides under the 1150cy dot
      const float pi = a2xbuf[s & 7][lane];
      const float pf = a2xbuf[s & 7][64 + lane];
      const float pg = a2xbuf[s & 7][128 + lane];
      const float po = a2xbuf[s & 7][192 + lane];

      const float hv = h2;
      float ai = 0.f, af = 0.f, ag = 0.f, ao = 0.f;
      DOT64
      ai += pi; af += pf; ag += pg; ao += po;

      c2 = sigm(af) * c2 + sigm(ai) * tanh_f(ag);
      h2 = sigm(ao) * tanh_f(c2);
      // lgkmcnt(0) drains the a2x reads -> slot s officially consumed.
      PUBLISH(f_2, s + 1);
      ob[(size_t)s * HH + lane] = fmaxf(h2 * m2v, 0.f);
    }
  } else {
    // ---- Xe (wid 1) / Xo (wid 2): Wih2 dot, parity-split ----
    float wi[HH], wf[HH], wg[HH], wo[HH];
    const float4* p = (const float4*)Wih2;
    WLOAD
    const float bi_i = bi2[lane] + bh2[lane];
    const float bi_f = bi2[64 + lane] + bh2[64 + lane];
    const float bi_g = bi2[128 + lane] + bh2[128 + lane];
    const float bi_o = bi2[192 + lane] + bh2[192 + lane];

    const int par = wid - 1;                       // 0 = even steps, 1 = odd
    volatile int* const myflag = par ? (volatile int*)&f_xo : (volatile int*)&f_xe;
    int s0 = 0, s2 = 0;
    for (int s = par; s < TT; s += 2) {
      WAITC(s0, f_h1, s + 1);
      const float hv = x2buf[s & 7][lane];

      float ai = bi_i, af = bi_f, ag = bi_g, ao = bi_o;
      DOT64

      WAITC(s2, f_2, s - 7);   // a2x slot (s&7) free? prev occupant s-8.
      a2xbuf[s & 7][lane] = ai;
      a2xbuf[s & 7][64 + lane] = af;
      a2xbuf[s & 7][128 + lane] = ag;
      a2xbuf[s & 7][192 + lane] = ao;
      // lgkmcnt(0) also drains the x2buf read -> x2 slot s consumed.
      PUBLISH(*myflag, s + 1);
    }
  }
#undef WAITC
#undef PUBLISH
}

extern "C" void kernel_launch(void* const* d_in, const int* in_sizes, int n_in,
                              void* d_out, int out_size, void* d_ws, size_t ws_size,
                              hipStream_t stream) {
  (void)in_sizes; (void)n_in; (void)out_size; (void)ws_size;
  const float* x     = (const float*)d_in[0];
  const float* W_ih1 = (const float*)d_in[1];
  const float* W_hh1 = (const float*)d_in[2];
  const float* b_ih1 = (const float*)d_in[3];
  const float* b_hh1 = (const float*)d_in[4];
  const float* W_ih2 = (const float*)d_in[5];
  const float* W_hh2 = (const float*)d_in[6];
  const float* b_ih2 = (const float*)d_in[7];
  const float* b_hh2 = (const float*)d_in[8];
  const float* mask1 = (const float*)d_in[9];
  const float* mask2 = (const float*)d_in[10];
  float* out = (float*)d_out;

  float* xg1 = (float*)d_ws;  // B*T*4H fp32 = 134,217,728 bytes

  xgemm<<<dim3(BB * TT / 256), dim3(256), 0, stream>>>(x, W_ih1, b_ih1, b_hh1, xg1);
  lstm2<<<dim3(BB), dim3(256), 0, stream>>>(xg1, W_hh1, W_ih2, W_hh2, b_ih2, b_hh2,
                                            mask1, mask2, out);
}